// Round 3
// baseline (1291.898 us; speedup 1.0000x reference)
//
#include <hip/hip_runtime.h>

#define Bb 2
#define Hh 16
#define Ss 2048
#define Dd 128
#define NWrd (Ss / 64)
#define NBLK (Bb * Hh * (Ss / 64))  // 1024 total workgroups

typedef _Float16 half_t;
typedef __attribute__((ext_vector_type(4))) float floatx4;
typedef __attribute__((ext_vector_type(8))) _Float16 halfx8;
typedef unsigned long long u64;

// ---- cast Q (scale*log2e folded -> scores feed v_exp_f32 directly) and K to f16 ----
__global__ __launch_bounds__(256) void cvt_qk_kernel(
    const float* __restrict__ Q, const float* __restrict__ K,
    const float* __restrict__ scale_p,
    half_t* __restrict__ Qh, half_t* __restrict__ Kh) {
  const float s = scale_p[0] * 1.4426950408889634f;  // fold log2(e): exp2 path
  size_t i = ((size_t)blockIdx.x * 256 + threadIdx.x) * 8;
  floatx4 a0 = *(const floatx4*)(Q + i);
  floatx4 a1 = *(const floatx4*)(Q + i + 4);
  halfx8 hq = {(half_t)(a0.x * s), (half_t)(a0.y * s), (half_t)(a0.z * s),
               (half_t)(a0.w * s), (half_t)(a1.x * s), (half_t)(a1.y * s),
               (half_t)(a1.z * s), (half_t)(a1.w * s)};
  *(halfx8*)(Qh + i) = hq;
  floatx4 b0 = *(const floatx4*)(K + i);
  floatx4 b1 = *(const floatx4*)(K + i + 4);
  halfx8 hk = {(half_t)b0.x, (half_t)b0.y, (half_t)b0.z, (half_t)b0.w,
               (half_t)b1.x, (half_t)b1.y, (half_t)b1.z, (half_t)b1.w};
  *(halfx8*)(Kh + i) = hk;
}

// ---- V transpose+cast: [B*H, S, D] f32 -> [B*H, D, S] f16 ----
__global__ __launch_bounds__(256) void vt_kernel(const float* __restrict__ V,
                                                 half_t* __restrict__ Vt) {
  __shared__ __align__(16) half_t t[64 * 72];
  const int bh = blockIdx.z;
  const int k0 = blockIdx.x * 64;
  const int d0 = blockIdx.y * 64;
  const int tid = threadIdx.x;
  const float* src = V + ((size_t)bh * Ss + k0) * Dd + d0;
  for (int idx = tid; idx < 64 * 16; idx += 256) {
    int r = idx >> 4;
    int c4 = (idx & 15) << 2;
    floatx4 v = *(const floatx4*)(src + (size_t)r * Dd + c4);
    t[(c4 + 0) * 72 + r] = (half_t)v.x;
    t[(c4 + 1) * 72 + r] = (half_t)v.y;
    t[(c4 + 2) * 72 + r] = (half_t)v.z;
    t[(c4 + 3) * 72 + r] = (half_t)v.w;
  }
  __syncthreads();
  half_t* dst = Vt + ((size_t)bh * Dd + d0) * Ss + k0;
  for (int idx = tid; idx < 64 * 8; idx += 256) {
    int r = idx >> 3;
    int c8 = (idx & 7) << 3;
    *(halfx8*)(dst + (size_t)r * Ss + c8) = *(const halfx8*)&t[r * 72 + c8];
  }
}

// ---- pack mask ints -> bit words (one wave per 64 columns) ----
__global__ __launch_bounds__(256) void mask_pack_kernel(
    const int* __restrict__ mask, u64* __restrict__ mb) {
  size_t w = (size_t)blockIdx.x * 4 + (threadIdx.x >> 6);
  int lane = threadIdx.x & 63;
  int m = mask[w * 64 + lane];
  u64 bal = __ballot(m != 0);
  if (lane == 0) mb[w] = bal;
}

// ---- fused attention: barrier-free, all operands direct from global (L2) ----
// Only LDS use is the per-wave-private Ps transpose scratch. The write->read
// handoff is wave-synchronous; an explicit lgkmcnt(0) fence (with "memory"
// clobber for compile-time ordering) replaces __syncthreads -> zero block
// barriers in the whole kernel.
__global__ __launch_bounds__(256, 4) void attn_kernel(
    const half_t* __restrict__ Qh, const half_t* __restrict__ Kh,
    const u64* __restrict__ Mb, const half_t* __restrict__ Vt,
    float* __restrict__ ctx_out, float* __restrict__ attn_out) {
  __shared__ __align__(16) half_t Ps[4 * 16 * 72];

  const int tid = threadIdx.x;
  const int wave = tid >> 6;
  const int lane = tid & 63;
  const int quad = lane >> 4;
  const int l16 = lane & 15;

  // XCD-chunked swizzle: all 32 q-chunks of a head land on ONE XCD's L2.
  // (1024 % 8 == 0 -> bijective)
  const int wg = blockIdx.x + 32 * (blockIdx.y + Hh * blockIdx.z);
  const int v = (wg & 7) * (NBLK / 8) + (wg >> 3);
  const int q0 = (v & 31) * 64;
  const int bh = v >> 5;            // 0 .. B*H-1
  const int bidx = bh >> 4;         // batch index (Hh == 16)

  const half_t* Qg = Qh + ((size_t)bh * Ss + q0) * Dd;
  const half_t* Kg = Kh + (size_t)bh * Ss * Dd;
  const half_t* Vtg = Vt + (size_t)bh * Dd * Ss;
  const u64* Mg = Mb + ((size_t)bidx * Ss + q0) * NWrd;

  // Q A-fragments straight from global (one-time 16KB/block, L2-hot)
  const int arow = 16 * wave + l16;
  halfx8 qa[4];
#pragma unroll
  for (int ks = 0; ks < 4; ++ks)
    qa[ks] = *(const halfx8*)(Qg + (size_t)arow * Dd + ks * 32 + quad * 8);

  const int lrow = 16 * wave + quad * 4;  // local C-layout row base
  const int qrow = q0 + lrow;             // global (within head)
  const u64* Mrow = Mg + (size_t)lrow * NWrd;
  float lacc[4] = {0.f, 0.f, 0.f, 0.f};

  // -------- pass 1: per-lane partial row sums of exp --------
  for (int kt = 0; kt < NWrd; ++kt) {
    const int k0 = kt * 64;
    u64 mw[4];
#pragma unroll
    for (int r = 0; r < 4; ++r) mw[r] = Mrow[(size_t)r * NWrd + kt];
#pragma unroll
    for (int nt = 0; nt < 4; ++nt) {
      const half_t* krow = Kg + (size_t)(k0 + nt * 16 + l16) * Dd + quad * 8;
      floatx4 acc = {0.f, 0.f, 0.f, 0.f};
#pragma unroll
      for (int ks = 0; ks < 4; ++ks) {
        halfx8 bf = *(const halfx8*)(krow + ks * 32);
        acc = __builtin_amdgcn_mfma_f32_16x16x32_f16(qa[ks], bf, acc, 0, 0, 0);
      }
      const int sh = nt * 16 + l16;
#pragma unroll
      for (int r = 0; r < 4; ++r) {
        float e = ((mw[r] >> sh) & 1) ? exp2f(acc[r]) : 0.0f;
        lacc[r] += e;  // reduce across l16 AFTER the loop
      }
    }
  }
  float inv[4];
#pragma unroll
  for (int r = 0; r < 4; ++r) {
    float s = lacc[r];
    s += __shfl_xor(s, 1);
    s += __shfl_xor(s, 2);
    s += __shfl_xor(s, 4);
    s += __shfl_xor(s, 8);
    inv[r] = 1.0f / s;
  }

  floatx4 cacc[8];
#pragma unroll
  for (int i = 0; i < 8; ++i) cacc[i] = (floatx4){0.f, 0.f, 0.f, 0.f};
  float* attn_row = attn_out + (size_t)bh * Ss * Ss + (size_t)qrow * Ss;

  // -------- pass 2: normalized attention out + fused PV --------
  for (int kt = 0; kt < NWrd; ++kt) {
    const int k0 = kt * 64;
    u64 mw[4];
#pragma unroll
    for (int r = 0; r < 4; ++r) mw[r] = Mrow[(size_t)r * NWrd + kt];
#pragma unroll
    for (int nt = 0; nt < 4; ++nt) {
      const half_t* krow = Kg + (size_t)(k0 + nt * 16 + l16) * Dd + quad * 8;
      floatx4 acc = {0.f, 0.f, 0.f, 0.f};
#pragma unroll
      for (int ks = 0; ks < 4; ++ks) {
        halfx8 bf = *(const halfx8*)(krow + ks * 32);
        acc = __builtin_amdgcn_mfma_f32_16x16x32_f16(qa[ks], bf, acc, 0, 0, 0);
      }
      const int sh = nt * 16 + l16;
#pragma unroll
      for (int r = 0; r < 4; ++r) {
        float p = ((mw[r] >> sh) & 1) ? exp2f(acc[r]) * inv[r] : 0.0f;
        __builtin_nontemporal_store(p, &attn_row[(size_t)r * Ss + k0 + sh]);
        Ps[wave * (16 * 72) + (quad * 4 + r) * 72 + sh] = (half_t)p;
      }
    }
    // wave-synchronous LDS handoff: runtime wait + compile-time ordering.
    asm volatile("s_waitcnt lgkmcnt(0)" ::: "memory");
    halfx8 pa0 = *(const halfx8*)&Ps[wave * (16 * 72) + l16 * 72 + quad * 8];
    halfx8 pa1 = *(const halfx8*)&Ps[wave * (16 * 72) + l16 * 72 + 32 + quad * 8];
#pragma unroll
    for (int nt2 = 0; nt2 < 8; ++nt2) {
      const half_t* vrow = Vtg + (size_t)(nt2 * 16 + l16) * Ss + k0 + quad * 8;
      halfx8 bv0 = *(const halfx8*)(vrow);
      cacc[nt2] = __builtin_amdgcn_mfma_f32_16x16x32_f16(pa0, bv0, cacc[nt2], 0, 0, 0);
      halfx8 bv1 = *(const halfx8*)(vrow + 32);
      cacc[nt2] = __builtin_amdgcn_mfma_f32_16x16x32_f16(pa1, bv1, cacc[nt2], 0, 0, 0);
    }
  }

  float* ctx = ctx_out + (size_t)bh * Ss * Dd;
#pragma unroll
  for (int nt2 = 0; nt2 < 8; ++nt2) {
#pragma unroll
    for (int r = 0; r < 4; ++r) {
      ctx[(size_t)(qrow + r) * Dd + nt2 * 16 + l16] = cacc[nt2][r];
    }
  }
}

extern "C" void kernel_launch(void* const* d_in, const int* in_sizes, int n_in,
                              void* d_out, int out_size, void* d_ws, size_t ws_size,
                              hipStream_t stream) {
  const float* Q = (const float*)d_in[0];
  const float* K = (const float*)d_in[1];
  const float* V = (const float*)d_in[2];
  const int* mask = (const int*)d_in[3];
  const float* scale = (const float*)d_in[4];
  float* ctx = (float*)d_out;
  float* attn = (float*)d_out + (size_t)Bb * Hh * Ss * Dd;

  const size_t nqk = (size_t)Bb * Hh * Ss * Dd;  // 8388608
  half_t* Qh = (half_t*)d_ws;
  half_t* Kh = Qh + nqk;
  half_t* Vt = Kh + nqk;
  u64* Mbits = (u64*)(Vt + nqk);  // 1 MB

  cvt_qk_kernel<<<nqk / (256 * 8), 256, 0, stream>>>(Q, K, scale, Qh, Kh);
  dim3 gt(Ss / 64, Dd / 64, Bb * Hh);
  vt_kernel<<<gt, 256, 0, stream>>>(V, Vt);
  mask_pack_kernel<<<((size_t)Bb * Ss * NWrd) / 4, 256, 0, stream>>>(mask, Mbits);
  dim3 gm(Ss / 64, Hh, Bb);
  attn_kernel<<<gm, 256, 0, stream>>>(Qh, Kh, Mbits, Vt, ctx, attn);
}

// Round 5
// 874.949 us; speedup vs baseline: 1.4765x; 1.4765x over previous
//
#include <hip/hip_runtime.h>

#define Bb 2
#define Hh 16
#define Ss 2048
#define Dd 128
#define NWrd (Ss / 64)
#define NBLK (Bb * Hh * (Ss / 64))  // 1024 total workgroups

typedef _Float16 half_t;
typedef __attribute__((ext_vector_type(4))) float floatx4;
typedef __attribute__((ext_vector_type(8))) _Float16 halfx8;
typedef unsigned long long u64;

// ---- cast Q (scale*log2e folded -> scores feed v_exp_f32 directly) and K to f16 ----
__global__ __launch_bounds__(256) void cvt_qk_kernel(
    const float* __restrict__ Q, const float* __restrict__ K,
    const float* __restrict__ scale_p,
    half_t* __restrict__ Qh, half_t* __restrict__ Kh) {
  const float s = scale_p[0] * 1.4426950408889634f;  // fold log2(e): exp2 path
  size_t i = ((size_t)blockIdx.x * 256 + threadIdx.x) * 8;
  floatx4 a0 = *(const floatx4*)(Q + i);
  floatx4 a1 = *(const floatx4*)(Q + i + 4);
  halfx8 hq = {(half_t)(a0.x * s), (half_t)(a0.y * s), (half_t)(a0.z * s),
               (half_t)(a0.w * s), (half_t)(a1.x * s), (half_t)(a1.y * s),
               (half_t)(a1.z * s), (half_t)(a1.w * s)};
  *(halfx8*)(Qh + i) = hq;
  floatx4 b0 = *(const floatx4*)(K + i);
  floatx4 b1 = *(const floatx4*)(K + i + 4);
  halfx8 hk = {(half_t)b0.x, (half_t)b0.y, (half_t)b0.z, (half_t)b0.w,
               (half_t)b1.x, (half_t)b1.y, (half_t)b1.z, (half_t)b1.w};
  *(halfx8*)(Kh + i) = hk;
}

// ---- V transpose+cast: [B*H, S, D] f32 -> [B*H, D, S] f16 ----
__global__ __launch_bounds__(256) void vt_kernel(const float* __restrict__ V,
                                                 half_t* __restrict__ Vt) {
  __shared__ __align__(16) half_t t[64 * 72];
  const int bh = blockIdx.z;
  const int k0 = blockIdx.x * 64;
  const int d0 = blockIdx.y * 64;
  const int tid = threadIdx.x;
  const float* src = V + ((size_t)bh * Ss + k0) * Dd + d0;
  for (int idx = tid; idx < 64 * 16; idx += 256) {
    int r = idx >> 4;
    int c4 = (idx & 15) << 2;
    floatx4 v = *(const floatx4*)(src + (size_t)r * Dd + c4);
    t[(c4 + 0) * 72 + r] = (half_t)v.x;
    t[(c4 + 1) * 72 + r] = (half_t)v.y;
    t[(c4 + 2) * 72 + r] = (half_t)v.z;
    t[(c4 + 3) * 72 + r] = (half_t)v.w;
  }
  __syncthreads();
  half_t* dst = Vt + ((size_t)bh * Dd + d0) * Ss + k0;
  for (int idx = tid; idx < 64 * 8; idx += 256) {
    int r = idx >> 3;
    int c8 = (idx & 7) << 3;
    *(halfx8*)(dst + (size_t)r * Ss + c8) = *(const halfx8*)&t[r * 72 + c8];
  }
}

// ---- pack mask ints -> bit words (one wave per 64 columns) ----
__global__ __launch_bounds__(256) void mask_pack_kernel(
    const int* __restrict__ mask, u64* __restrict__ mb) {
  size_t w = (size_t)blockIdx.x * 4 + (threadIdx.x >> 6);
  int lane = threadIdx.x & 63;
  int m = mask[w * 64 + lane];
  u64 bal = __ballot(m != 0);
  if (lane == 0) mb[w] = bal;
}

// ================= fused single-QK^T kernel (needs Pw workspace) =============
// Phase A: QK^T once, exp2, accumulate row sums, store UNNORMALIZED p (f16)
//          to Pw via the Ps transpose (so Pw rows are in A-frag orientation).
// Phase B: read Pw rows back (coalesced), scale by inv, write attn f32
//          (coalesced vector stores), PV-MFMA with V staged in LDS.
// LDS union: phase A = Ks+Ps (26624 B), phase B = Vts (18432 B).
__global__ __launch_bounds__(256, 4) void attn_fused(
    const half_t* __restrict__ Qh, const half_t* __restrict__ Kh,
    const u64* __restrict__ Mb, const half_t* __restrict__ Vt,
    half_t* __restrict__ Pw, float* __restrict__ ctx_out,
    float* __restrict__ attn_out) {
  __shared__ __align__(16) half_t smem[64 * 136 + 4 * 16 * 72];  // 26624 B
  __shared__ float invs[64];
  half_t* Ks = smem;
  half_t* Ps = smem + 64 * 136;
  half_t* Vts = smem;  // phase-B alias: 128*72 halfs = 18432 B <= 26624 B

  const int tid = threadIdx.x;
  const int wave = tid >> 6;
  const int lane = tid & 63;
  const int quad = lane >> 4;
  const int l16 = lane & 15;

  // XCD-chunked bijective swizzle (1024 % 8 == 0)
  const int wg = blockIdx.x + 32 * (blockIdx.y + Hh * blockIdx.z);
  const int v = (wg & 7) * (NBLK / 8) + (wg >> 3);
  const int q0 = (v & 31) * 64;
  const int bh = v >> 5;
  const int bidx = bh >> 4;  // Hh == 16

  const half_t* Qg = Qh + ((size_t)bh * Ss + q0) * Dd;
  const half_t* Kg = Kh + (size_t)bh * Ss * Dd;
  const half_t* Vtg = Vt + (size_t)bh * Dd * Ss;
  const u64* Mg = Mb + ((size_t)bidx * Ss + q0) * NWrd;
  half_t* Pwg = Pw + ((size_t)bh * Ss + q0) * Ss;

  // Q A-fragments direct from global (one-time, L2-hot)
  const int arow = 16 * wave + l16;
  halfx8 qa[4];
#pragma unroll
  for (int ks = 0; ks < 4; ++ks)
    qa[ks] = *(const halfx8*)(Qg + (size_t)arow * Dd + ks * 32 + quad * 8);

  const int lrow = 16 * wave + quad * 4;  // C-layout row base
  const int qrow = q0 + lrow;
  const u64* Mrow = Mg + (size_t)lrow * NWrd;
  float lacc[4] = {0.f, 0.f, 0.f, 0.f};

  // per-lane Pw row base (A-frag orientation: row arow, col quad*8 (+ks*32))
  half_t* Pl = Pwg + (size_t)arow * Ss + quad * 8;

  const int s_r = tid >> 4;         // staging row 0..15
  const int s_c = (tid & 15) << 3;  // staging col (halfs)

  halfx8 kpre[4];
#pragma unroll
  for (int it = 0; it < 4; ++it)
    kpre[it] = *(const halfx8*)(Kg + (size_t)(s_r + it * 16) * Dd + s_c);

  // -------- phase A: QK^T once, exp2, row sums, Pw store --------
  for (int kt = 0; kt < NWrd; ++kt) {
    const int k0 = kt * 64;
    __syncthreads();
#pragma unroll
    for (int it = 0; it < 4; ++it)
      *(halfx8*)&Ks[(s_r + it * 16) * 136 + s_c] = kpre[it];
    if (kt + 1 < NWrd) {
#pragma unroll
      for (int it = 0; it < 4; ++it)
        kpre[it] = *(const halfx8*)(Kg + (size_t)(k0 + 64 + s_r + it * 16) * Dd + s_c);
    }
    u64 mw[4];
#pragma unroll
    for (int r = 0; r < 4; ++r) mw[r] = Mrow[(size_t)r * NWrd + kt];
    __syncthreads();
#pragma unroll
    for (int nt = 0; nt < 4; ++nt) {
      floatx4 acc = {0.f, 0.f, 0.f, 0.f};
#pragma unroll
      for (int ks = 0; ks < 4; ++ks) {
        halfx8 bf = *(const halfx8*)&Ks[(nt * 16 + l16) * 136 + ks * 32 + quad * 8];
        acc = __builtin_amdgcn_mfma_f32_16x16x32_f16(qa[ks], bf, acc, 0, 0, 0);
      }
      const int sh = nt * 16 + l16;
#pragma unroll
      for (int r = 0; r < 4; ++r) {
        float e = ((mw[r] >> sh) & 1) ? exp2f(acc[r]) : 0.0f;  // p <= e^~6, f16-safe
        lacc[r] += e;
        Ps[wave * (16 * 72) + (quad * 4 + r) * 72 + sh] = (half_t)e;
      }
    }
    // wave-synchronous Ps handoff (validated round 3), then coalesced Pw store
    asm volatile("s_waitcnt lgkmcnt(0)" ::: "memory");
    halfx8 pa0 = *(const halfx8*)&Ps[wave * (16 * 72) + l16 * 72 + quad * 8];
    halfx8 pa1 = *(const halfx8*)&Ps[wave * (16 * 72) + l16 * 72 + 32 + quad * 8];
    *(halfx8*)(Pl + k0) = pa0;
    *(halfx8*)(Pl + k0 + 32) = pa1;
  }

  float inv[4];
#pragma unroll
  for (int r = 0; r < 4; ++r) {
    float s = lacc[r];
    s += __shfl_xor(s, 1);
    s += __shfl_xor(s, 2);
    s += __shfl_xor(s, 4);
    s += __shfl_xor(s, 8);
    inv[r] = 1.0f / s;
  }
  // redistribute inv: phase B lane (quad,l16) needs inv of row l16
#pragma unroll
  for (int r = 0; r < 4; ++r) invs[wave * 16 + quad * 4 + r] = inv[r];
  __syncthreads();  // phase transition: invs visible; Ps reads drained
  const float invf = invs[wave * 16 + l16];

  // -------- phase B: read Pw, scale, attn store, PV with staged V --------
  floatx4 cacc[8];
#pragma unroll
  for (int i = 0; i < 8; ++i) cacc[i] = (floatx4){0.f, 0.f, 0.f, 0.f};
  // FIXED (round-4 bug): attn row base must include the q0 tile offset.
  float* arow_p = attn_out + ((size_t)bh * Ss + q0 + arow) * Ss + quad * 8;

  const int v_r = tid >> 3;          // V staging row (4 its -> 0..127)
  const int v_c = (tid & 7) << 3;    // col halfs
  halfx8 vpre[4];
#pragma unroll
  for (int it = 0; it < 4; ++it)
    vpre[it] = *(const halfx8*)(Vtg + (size_t)(v_r + it * 32) * Ss + v_c);

  for (int kt = 0; kt < NWrd; ++kt) {
    const int k0 = kt * 64;
    __syncthreads();
#pragma unroll
    for (int it = 0; it < 4; ++it)
      *(halfx8*)&Vts[(v_r + it * 32) * 72 + v_c] = vpre[it];
    if (kt + 1 < NWrd) {
#pragma unroll
      for (int it = 0; it < 4; ++it)
        vpre[it] = *(const halfx8*)(Vtg + (size_t)(v_r + it * 32) * Ss + k0 + 64 + v_c);
    }
    // P rows come back coalesced, already in A-frag orientation
    halfx8 pa0 = *(const halfx8*)(Pl + k0);
    halfx8 pa1 = *(const halfx8*)(Pl + k0 + 32);
    __syncthreads();

    // scale by inv (f32), write attn f32 coalesced, repack f16 for MFMA
    floatx4 f0a, f0b, f1a, f1b;
    halfx8 ph0, ph1;
#pragma unroll
    for (int j = 0; j < 4; ++j) {
      f0a[j] = (float)pa0[j] * invf;
      f0b[j] = (float)pa0[j + 4] * invf;
      f1a[j] = (float)pa1[j] * invf;
      f1b[j] = (float)pa1[j + 4] * invf;
    }
#pragma unroll
    for (int j = 0; j < 4; ++j) {
      ph0[j] = (half_t)f0a[j];
      ph0[j + 4] = (half_t)f0b[j];
      ph1[j] = (half_t)f1a[j];
      ph1[j + 4] = (half_t)f1b[j];
    }
    __builtin_nontemporal_store(f0a, (floatx4*)(arow_p + k0));
    __builtin_nontemporal_store(f0b, (floatx4*)(arow_p + k0 + 4));
    __builtin_nontemporal_store(f1a, (floatx4*)(arow_p + k0 + 32));
    __builtin_nontemporal_store(f1b, (floatx4*)(arow_p + k0 + 36));

#pragma unroll
    for (int nt2 = 0; nt2 < 8; ++nt2) {
      halfx8 bv0 = *(const halfx8*)&Vts[(nt2 * 16 + l16) * 72 + quad * 8];
      cacc[nt2] = __builtin_amdgcn_mfma_f32_16x16x32_f16(ph0, bv0, cacc[nt2], 0, 0, 0);
      halfx8 bv1 = *(const halfx8*)&Vts[(nt2 * 16 + l16) * 72 + 32 + quad * 8];
      cacc[nt2] = __builtin_amdgcn_mfma_f32_16x16x32_f16(ph1, bv1, cacc[nt2], 0, 0, 0);
    }
  }

  float* ctx = ctx_out + (size_t)bh * Ss * Dd;
#pragma unroll
  for (int nt2 = 0; nt2 < 8; ++nt2) {
#pragma unroll
    for (int r = 0; r < 4; ++r) {
      ctx[(size_t)(qrow + r) * Dd + nt2 * 16 + l16] = cacc[nt2][r];
    }
  }
}

// ================= fallback: proven round-1 two-pass kernel (exp2 fold) =====
__global__ __launch_bounds__(256, 4) void attn_2pass(
    const half_t* __restrict__ Qh, const half_t* __restrict__ Kh,
    const u64* __restrict__ Mb, const half_t* __restrict__ Vt,
    float* __restrict__ ctx_out, float* __restrict__ attn_out) {
  __shared__ __align__(16) half_t Ks[64 * 136];
  __shared__ __align__(16) half_t Ps[4 * 16 * 72];

  const int tid = threadIdx.x;
  const int wave = tid >> 6;
  const int lane = tid & 63;
  const int quad = lane >> 4;
  const int l16 = lane & 15;

  const int wg = blockIdx.x + 32 * (blockIdx.y + Hh * blockIdx.z);
  const int v = (wg & 7) * (NBLK / 8) + (wg >> 3);
  const int q0 = (v & 31) * 64;
  const int bh = v >> 5;
  const int bidx = bh >> 4;

  const half_t* Qg = Qh + ((size_t)bh * Ss + q0) * Dd;
  const half_t* Kg = Kh + (size_t)bh * Ss * Dd;
  const half_t* Vtg = Vt + (size_t)bh * Dd * Ss;
  const u64* Mg = Mb + ((size_t)bidx * Ss + q0) * NWrd;

  const int arow = 16 * wave + l16;
  halfx8 qa[4];
#pragma unroll
  for (int ks = 0; ks < 4; ++ks)
    qa[ks] = *(const halfx8*)(Qg + (size_t)arow * Dd + ks * 32 + quad * 8);

  const int lrow = 16 * wave + quad * 4;
  const int qrow = q0 + lrow;
  const u64* Mrow = Mg + (size_t)lrow * NWrd;
  float lacc[4] = {0.f, 0.f, 0.f, 0.f};

  const int s_r = tid >> 4;
  const int s_c = (tid & 15) << 3;

  halfx8 kpre[4];
#pragma unroll
  for (int it = 0; it < 4; ++it)
    kpre[it] = *(const halfx8*)(Kg + (size_t)(s_r + it * 16) * Dd + s_c);

  for (int kt = 0; kt < NWrd; ++kt) {
    const int k0 = kt * 64;
    __syncthreads();
#pragma unroll
    for (int it = 0; it < 4; ++it)
      *(halfx8*)&Ks[(s_r + it * 16) * 136 + s_c] = kpre[it];
    if (kt + 1 < NWrd) {
#pragma unroll
      for (int it = 0; it < 4; ++it)
        kpre[it] = *(const halfx8*)(Kg + (size_t)(k0 + 64 + s_r + it * 16) * Dd + s_c);
    }
    u64 mw[4];
#pragma unroll
    for (int r = 0; r < 4; ++r) mw[r] = Mrow[(size_t)r * NWrd + kt];
    __syncthreads();
#pragma unroll
    for (int nt = 0; nt < 4; ++nt) {
      floatx4 acc = {0.f, 0.f, 0.f, 0.f};
#pragma unroll
      for (int ks = 0; ks < 4; ++ks) {
        halfx8 bf = *(const halfx8*)&Ks[(nt * 16 + l16) * 136 + ks * 32 + quad * 8];
        acc = __builtin_amdgcn_mfma_f32_16x16x32_f16(qa[ks], bf, acc, 0, 0, 0);
      }
      const int sh = nt * 16 + l16;
#pragma unroll
      for (int r = 0; r < 4; ++r) {
        float e = ((mw[r] >> sh) & 1) ? exp2f(acc[r]) : 0.0f;
        lacc[r] += e;
      }
    }
  }
  float inv[4];
#pragma unroll
  for (int r = 0; r < 4; ++r) {
    float s = lacc[r];
    s += __shfl_xor(s, 1);
    s += __shfl_xor(s, 2);
    s += __shfl_xor(s, 4);
    s += __shfl_xor(s, 8);
    inv[r] = 1.0f / s;
  }

  floatx4 cacc[8];
#pragma unroll
  for (int i = 0; i < 8; ++i) cacc[i] = (floatx4){0.f, 0.f, 0.f, 0.f};
  float* attn_row = attn_out + (size_t)bh * Ss * Ss + (size_t)qrow * Ss;

#pragma unroll
  for (int it = 0; it < 4; ++it)
    kpre[it] = *(const halfx8*)(Kg + (size_t)(s_r + it * 16) * Dd + s_c);

  for (int kt = 0; kt < NWrd; ++kt) {
    const int k0 = kt * 64;
    __syncthreads();
#pragma unroll
    for (int it = 0; it < 4; ++it)
      *(halfx8*)&Ks[(s_r + it * 16) * 136 + s_c] = kpre[it];
    if (kt + 1 < NWrd) {
#pragma unroll
      for (int it = 0; it < 4; ++it)
        kpre[it] = *(const halfx8*)(Kg + (size_t)(k0 + 64 + s_r + it * 16) * Dd + s_c);
    }
    u64 mw[4];
#pragma unroll
    for (int r = 0; r < 4; ++r) mw[r] = Mrow[(size_t)r * NWrd + kt];
    __syncthreads();
#pragma unroll
    for (int nt = 0; nt < 4; ++nt) {
      floatx4 acc = {0.f, 0.f, 0.f, 0.f};
#pragma unroll
      for (int ks = 0; ks < 4; ++ks) {
        halfx8 bf = *(const halfx8*)&Ks[(nt * 16 + l16) * 136 + ks * 32 + quad * 8];
        acc = __builtin_amdgcn_mfma_f32_16x16x32_f16(qa[ks], bf, acc, 0, 0, 0);
      }
      const int sh = nt * 16 + l16;
#pragma unroll
      for (int r = 0; r < 4; ++r) {
        float p = ((mw[r] >> sh) & 1) ? exp2f(acc[r]) * inv[r] : 0.0f;
        __builtin_nontemporal_store(p, &attn_row[(size_t)r * Ss + k0 + sh]);
        Ps[wave * (16 * 72) + (quad * 4 + r) * 72 + sh] = (half_t)p;
      }
    }
    asm volatile("s_waitcnt lgkmcnt(0)" ::: "memory");
    halfx8 pa0 = *(const halfx8*)&Ps[wave * (16 * 72) + l16 * 72 + quad * 8];
    halfx8 pa1 = *(const halfx8*)&Ps[wave * (16 * 72) + l16 * 72 + 32 + quad * 8];
#pragma unroll
    for (int nt2 = 0; nt2 < 8; ++nt2) {
      const half_t* vrow = Vtg + (size_t)(nt2 * 16 + l16) * Ss + k0 + quad * 8;
      halfx8 bv0 = *(const halfx8*)(vrow);
      cacc[nt2] = __builtin_amdgcn_mfma_f32_16x16x32_f16(pa0, bv0, cacc[nt2], 0, 0, 0);
      halfx8 bv1 = *(const halfx8*)(vrow + 32);
      cacc[nt2] = __builtin_amdgcn_mfma_f32_16x16x32_f16(pa1, bv1, cacc[nt2], 0, 0, 0);
    }
  }

  float* ctx = ctx_out + (size_t)bh * Ss * Dd;
#pragma unroll
  for (int nt2 = 0; nt2 < 8; ++nt2) {
#pragma unroll
    for (int r = 0; r < 4; ++r) {
      ctx[(size_t)(qrow + r) * Dd + nt2 * 16 + l16] = cacc[nt2][r];
    }
  }
}

extern "C" void kernel_launch(void* const* d_in, const int* in_sizes, int n_in,
                              void* d_out, int out_size, void* d_ws, size_t ws_size,
                              hipStream_t stream) {
  const float* Q = (const float*)d_in[0];
  const float* K = (const float*)d_in[1];
  const float* V = (const float*)d_in[2];
  const int* mask = (const int*)d_in[3];
  const float* scale = (const float*)d_in[4];
  float* ctx = (float*)d_out;
  float* attn = (float*)d_out + (size_t)Bb * Hh * Ss * Dd;

  const size_t nqk = (size_t)Bb * Hh * Ss * Dd;      // 8388608
  const size_t nmask = (size_t)Bb * Ss * NWrd;       // 131072 words
  const size_t npw = (size_t)Bb * Hh * Ss * Ss;      // 134217728 halfs
  half_t* Qh = (half_t*)d_ws;
  half_t* Kh = Qh + nqk;
  half_t* Vt = Kh + nqk;
  u64* Mbits = (u64*)(Vt + nqk);
  half_t* Pw = (half_t*)(Mbits + nmask);

  const size_t need = 3 * nqk * sizeof(half_t) + nmask * sizeof(u64) +
                      npw * sizeof(half_t);  // ~320 MB

  cvt_qk_kernel<<<nqk / (256 * 8), 256, 0, stream>>>(Q, K, scale, Qh, Kh);
  dim3 gt(Ss / 64, Dd / 64, Bb * Hh);
  vt_kernel<<<gt, 256, 0, stream>>>(V, Vt);
  mask_pack_kernel<<<(nmask) / 4, 256, 0, stream>>>(mask, Mbits);
  dim3 gm(Ss / 64, Hh, Bb);
  if (ws_size >= need) {
    attn_fused<<<gm, 256, 0, stream>>>(Qh, Kh, Mbits, Vt, Pw, ctx, attn);
  } else {
    attn_2pass<<<gm, 256, 0, stream>>>(Qh, Kh, Mbits, Vt, ctx, attn);
  }
}